// Round 1
// baseline (405.320 us; speedup 1.0000x reference)
//
#include <hip/hip_runtime.h>
#include <math.h>

#define BB 32
#define CC 128
#define HW 1024
#define NH 4
#define DH 32
#define NG 32
#define TPG 4096   // (C/G)*H*W elements per group

// ---------------- GroupNorm ----------------
__global__ __launch_bounds__(256) void gn_kernel(const float* __restrict__ x,
    const float* __restrict__ gw, const float* __restrict__ gb,
    float* __restrict__ xn) {
  int blk = blockIdx.x;          // b*NG + g
  int b = blk >> 5, g = blk & 31;
  const float4* xp4 = (const float4*)(x + ((size_t)(b * CC + g * 4)) * HW);
  float s = 0.f, s2 = 0.f;
  float4 v[4];
  #pragma unroll
  for (int i = 0; i < 4; ++i) {
    v[i] = xp4[threadIdx.x + i * 256];
    s  += v[i].x + v[i].y + v[i].z + v[i].w;
    s2 += v[i].x * v[i].x + v[i].y * v[i].y + v[i].z * v[i].z + v[i].w * v[i].w;
  }
  #pragma unroll
  for (int off = 32; off; off >>= 1) {
    s  += __shfl_down(s, off, 64);
    s2 += __shfl_down(s2, off, 64);
  }
  __shared__ float ls[8], ls2[8];
  int lane = threadIdx.x & 63, wid = threadIdx.x >> 6;
  if (lane == 0) { ls[wid] = s; ls2[wid] = s2; }
  __syncthreads();
  if (threadIdx.x == 0) {
    float a  = ls[0] + ls[1] + ls[2] + ls[3];
    float a2 = ls2[0] + ls2[1] + ls2[2] + ls2[3];
    float mu = a * (1.f / TPG);
    float var = a2 * (1.f / TPG) - mu * mu;
    ls[0] = mu;
    ls2[0] = rsqrtf(var + 1e-5f);
  }
  __syncthreads();
  float mu = ls[0], rstd = ls2[0];
  float4* xo4 = (float4*)(xn + ((size_t)(b * CC + g * 4)) * HW);
  #pragma unroll
  for (int i = 0; i < 4; ++i) {
    int idx = threadIdx.x + i * 256;       // float4 index in [0,1024)
    int c = g * 4 + (idx >> 8);            // 256 float4 per channel
    float w = gw[c], bv = gb[c];
    float4 o;
    o.x = (v[i].x - mu) * rstd * w + bv;
    o.y = (v[i].y - mu) * rstd * w + bv;
    o.z = (v[i].z - mu) * rstd * w + bv;
    o.w = (v[i].w - mu) * rstd * w + bv;
    xo4[idx] = o;
  }
}

// ---------------- Tiled fp32 GEMM: Out[o,t] = sum_c A[o,c] * X[c,t] ----------------
// A: O x 128 row-major. X: per-batch 128 x 1024. Out: per-batch O x 1024.
// EPI==1: Out += bias[o] + resid[o,t]
template<int EPI>
__global__ __launch_bounds__(256) void gemm_kernel(
    const float* __restrict__ A, const float* __restrict__ Xin,
    float* __restrict__ Out, int O,
    const float* __restrict__ bias, const float* __restrict__ resid) {
  int b = blockIdx.z;
  int o0 = blockIdx.y * 64;
  int t0 = blockIdx.x * 64;
  const float* X = Xin + (size_t)b * CC * HW;
  float* Op = Out + (size_t)b * O * HW;

  __shared__ float Ws[32][68];  // [k][o], transposed store
  __shared__ float Xs[32][68];  // [k][t]
  int tx = threadIdx.x & 15, ty = threadIdx.x >> 4;
  float acc[4][4] = {};

  for (int kc = 0; kc < CC; kc += 32) {
    __syncthreads();
    #pragma unroll
    for (int j = 0; j < 2; ++j) {
      int f = threadIdx.x + j * 256;
      // W tile: 64 rows x 32 k = 512 float4
      int wrow = f >> 3, wk = (f & 7) * 4;
      float4 wv = *(const float4*)&A[(size_t)(o0 + wrow) * CC + kc + wk];
      Ws[wk + 0][wrow] = wv.x; Ws[wk + 1][wrow] = wv.y;
      Ws[wk + 2][wrow] = wv.z; Ws[wk + 3][wrow] = wv.w;
      // X tile: 32 rows x 64 t = 512 float4
      int xrow = f >> 4, xt = (f & 15) * 4;
      float4 xv = *(const float4*)&X[(size_t)(kc + xrow) * HW + t0 + xt];
      *(float4*)&Xs[xrow][xt] = xv;
    }
    __syncthreads();
    #pragma unroll
    for (int k = 0; k < 32; ++k) {
      float4 a4 = *(const float4*)&Ws[k][ty * 4];
      float4 b4 = *(const float4*)&Xs[k][tx * 4];
      float av[4] = {a4.x, a4.y, a4.z, a4.w};
      float bv[4] = {b4.x, b4.y, b4.z, b4.w};
      #pragma unroll
      for (int i = 0; i < 4; ++i)
        #pragma unroll
        for (int j = 0; j < 4; ++j)
          acc[i][j] = fmaf(av[i], bv[j], acc[i][j]);
    }
  }
  #pragma unroll
  for (int i = 0; i < 4; ++i) {
    int o = o0 + ty * 4 + i;
    float* op = Op + (size_t)o * HW + t0 + tx * 4;
    float4 r;
    r.x = acc[i][0]; r.y = acc[i][1]; r.z = acc[i][2]; r.w = acc[i][3];
    if (EPI) {
      float bs = bias[o];
      const float4 rv = *(const float4*)(resid + (size_t)b * CC * HW + (size_t)o * HW + t0 + tx * 4);
      r.x += bs + rv.x; r.y += bs + rv.y; r.z += bs + rv.z; r.w += bs + rv.w;
    }
    *(float4*)op = r;
  }
}

// ---------------- Flash attention, fp32, one thread per query row ----------------
__global__ __launch_bounds__(128) void attn_kernel(
    const float* __restrict__ qkv, float* __restrict__ hout) {
  int tt0 = blockIdx.x * 128;
  int h = blockIdx.y;
  int b = blockIdx.z;
  const float* base = qkv + ((size_t)b * 384 + (size_t)h * 96) * HW;
  const float* Qp = base;
  const float* Kp = base + 32 * HW;
  const float* Vp = base + 64 * HW;
  int t = tt0 + threadIdx.x;

  float q[32];
  #pragma unroll
  for (int c = 0; c < 32; ++c) q[c] = Qp[(size_t)c * HW + t] * (1.f / 32.f);

  float acc[32] = {};
  float m = -1e30f, l = 0.f;

  __shared__ float Ks[32][36];  // [s][c]
  __shared__ float Vs[32][36];  // [s][c]

  for (int s0 = 0; s0 < HW; s0 += 32) {
    __syncthreads();
    #pragma unroll
    for (int j = 0; j < 2; ++j) {
      int f = threadIdx.x + j * 128;   // 0..255
      int c = f >> 3, sb = (f & 7) * 4;
      float4 kv = *(const float4*)&Kp[(size_t)c * HW + s0 + sb];
      float4 vv = *(const float4*)&Vp[(size_t)c * HW + s0 + sb];
      Ks[sb + 0][c] = kv.x; Ks[sb + 1][c] = kv.y; Ks[sb + 2][c] = kv.z; Ks[sb + 3][c] = kv.w;
      Vs[sb + 0][c] = vv.x; Vs[sb + 1][c] = vv.y; Vs[sb + 2][c] = vv.z; Vs[sb + 3][c] = vv.w;
    }
    __syncthreads();

    float sc[32];
    float tmax = -1e30f;
    #pragma unroll
    for (int s = 0; s < 32; ++s) {
      float d = 0.f;
      #pragma unroll
      for (int c4 = 0; c4 < 8; ++c4) {
        float4 kk = *(const float4*)&Ks[s][c4 * 4];
        d = fmaf(q[c4 * 4 + 0], kk.x, d);
        d = fmaf(q[c4 * 4 + 1], kk.y, d);
        d = fmaf(q[c4 * 4 + 2], kk.z, d);
        d = fmaf(q[c4 * 4 + 3], kk.w, d);
      }
      sc[s] = d;
      tmax = fmaxf(tmax, d);
    }
    float mnew = fmaxf(m, tmax);
    float corr = __expf(m - mnew);
    l *= corr;
    #pragma unroll
    for (int c = 0; c < 32; ++c) acc[c] *= corr;
    m = mnew;
    #pragma unroll
    for (int s = 0; s < 32; ++s) {
      float p = __expf(sc[s] - m);
      l += p;
      #pragma unroll
      for (int c4 = 0; c4 < 8; ++c4) {
        float4 vv = *(const float4*)&Vs[s][c4 * 4];
        acc[c4 * 4 + 0] = fmaf(p, vv.x, acc[c4 * 4 + 0]);
        acc[c4 * 4 + 1] = fmaf(p, vv.y, acc[c4 * 4 + 1]);
        acc[c4 * 4 + 2] = fmaf(p, vv.z, acc[c4 * 4 + 2]);
        acc[c4 * 4 + 3] = fmaf(p, vv.w, acc[c4 * 4 + 3]);
      }
    }
  }
  float rinv = 1.f / l;
  float* op = hout + ((size_t)b * CC + (size_t)h * DH) * HW + t;
  #pragma unroll
  for (int c = 0; c < 32; ++c) op[(size_t)c * HW] = acc[c] * rinv;
}

extern "C" void kernel_launch(void* const* d_in, const int* in_sizes, int n_in,
                              void* d_out, int out_size, void* d_ws, size_t ws_size,
                              hipStream_t stream) {
  (void)in_sizes; (void)n_in; (void)out_size; (void)ws_size;
  const float* x     = (const float*)d_in[0];
  const float* gw    = (const float*)d_in[1];
  const float* gb    = (const float*)d_in[2];
  const float* qkvw  = (const float*)d_in[3];
  const float* projw = (const float*)d_in[4];
  const float* projb = (const float*)d_in[5];
  float* out = (float*)d_out;

  float* xn     = (float*)d_ws;                       // 16 MB, reused as hout
  float* qkvbuf = xn + (size_t)BB * CC * HW;          // 48 MB

  gn_kernel<<<dim3(BB * NG), 256, 0, stream>>>(x, gw, gb, xn);
  gemm_kernel<0><<<dim3(HW / 64, 384 / 64, BB), 256, 0, stream>>>(qkvw, xn, qkvbuf, 384, nullptr, nullptr);
  attn_kernel<<<dim3(HW / 128, NH, BB), 128, 0, stream>>>(qkvbuf, xn);
  gemm_kernel<1><<<dim3(HW / 64, CC / 64, BB), 256, 0, stream>>>(projw, xn, out, CC, projb, x);
}

// Round 3
// 177.489 us; speedup vs baseline: 2.2836x; 2.2836x over previous
//
#include <hip/hip_runtime.h>
#include <math.h>

#define BB 32
#define CC 128
#define HW 1024
#define NG 32
#define TPG 4096

typedef __attribute__((ext_vector_type(8))) short fragAB;
typedef __attribute__((ext_vector_type(4))) float fragC;

__device__ __forceinline__ ushort f2bf(float f) {
  union { float f; uint u; } v; v.f = f;
  uint r = v.u + 0x7FFFu + ((v.u >> 16) & 1u);
  return (ushort)(r >> 16);
}

// ---------------- GroupNorm ----------------
__global__ __launch_bounds__(256) void gn_kernel(const float* __restrict__ x,
    const float* __restrict__ gw, const float* __restrict__ gb,
    float* __restrict__ xn) {
  int blk = blockIdx.x;          // b*NG + g
  int b = blk >> 5, g = blk & 31;
  const float4* xp4 = (const float4*)(x + ((size_t)(b * CC + g * 4)) * HW);
  float s = 0.f, s2 = 0.f;
  float4 v[4];
  #pragma unroll
  for (int i = 0; i < 4; ++i) {
    v[i] = xp4[threadIdx.x + i * 256];
    s  += v[i].x + v[i].y + v[i].z + v[i].w;
    s2 += v[i].x * v[i].x + v[i].y * v[i].y + v[i].z * v[i].z + v[i].w * v[i].w;
  }
  #pragma unroll
  for (int off = 32; off; off >>= 1) {
    s  += __shfl_down(s, off, 64);
    s2 += __shfl_down(s2, off, 64);
  }
  __shared__ float ls[8], ls2[8];
  int lane = threadIdx.x & 63, wid = threadIdx.x >> 6;
  if (lane == 0) { ls[wid] = s; ls2[wid] = s2; }
  __syncthreads();
  if (threadIdx.x == 0) {
    float a  = ls[0] + ls[1] + ls[2] + ls[3];
    float a2 = ls2[0] + ls2[1] + ls2[2] + ls2[3];
    float mu = a * (1.f / TPG);
    float var = a2 * (1.f / TPG) - mu * mu;
    ls[0] = mu;
    ls2[0] = rsqrtf(var + 1e-5f);
  }
  __syncthreads();
  float mu = ls[0], rstd = ls2[0];
  float4* xo4 = (float4*)(xn + ((size_t)(b * CC + g * 4)) * HW);
  #pragma unroll
  for (int i = 0; i < 4; ++i) {
    int idx = threadIdx.x + i * 256;
    int c = g * 4 + (idx >> 8);
    float w = gw[c], bv = gb[c];
    float4 o;
    o.x = (v[i].x - mu) * rstd * w + bv;
    o.y = (v[i].y - mu) * rstd * w + bv;
    o.z = (v[i].z - mu) * rstd * w + bv;
    o.w = (v[i].w - mu) * rstd * w + bv;
    xo4[idx] = o;
  }
}

// ---------------- Tiled fp32 GEMM: Out[o,t] = sum_c A[o,c] * X[c,t] ----------------
// BF16OUT: write bf16, with q channels (o%96 < 32) pre-scaled by 1/32
//          (reference: logits = (q.k)/dh, dh=32).
// EPI: Out += bias[o] + resid[o,t] (fp32 out).
template<int EPI, int BF16OUT>
__global__ __launch_bounds__(256) void gemm_kernel(
    const float* __restrict__ A, const float* __restrict__ Xin,
    void* __restrict__ OutV, int O,
    const float* __restrict__ bias, const float* __restrict__ resid) {
  int b = blockIdx.z;
  int o0 = blockIdx.y * 64;
  int t0 = blockIdx.x * 64;
  const float* X = Xin + (size_t)b * CC * HW;

  __shared__ float Ws[32][68];
  __shared__ float Xs[32][68];
  int tx = threadIdx.x & 15, ty = threadIdx.x >> 4;
  float acc[4][4] = {};

  for (int kc = 0; kc < CC; kc += 32) {
    __syncthreads();
    #pragma unroll
    for (int j = 0; j < 2; ++j) {
      int f = threadIdx.x + j * 256;
      int wrow = f >> 3, wk = (f & 7) * 4;
      float4 wv = *(const float4*)&A[(size_t)(o0 + wrow) * CC + kc + wk];
      Ws[wk + 0][wrow] = wv.x; Ws[wk + 1][wrow] = wv.y;
      Ws[wk + 2][wrow] = wv.z; Ws[wk + 3][wrow] = wv.w;
      int xrow = f >> 4, xt = (f & 15) * 4;
      float4 xv = *(const float4*)&X[(size_t)(kc + xrow) * HW + t0 + xt];
      *(float4*)&Xs[xrow][xt] = xv;
    }
    __syncthreads();
    #pragma unroll
    for (int k = 0; k < 32; ++k) {
      float4 a4 = *(const float4*)&Ws[k][ty * 4];
      float4 b4 = *(const float4*)&Xs[k][tx * 4];
      float av[4] = {a4.x, a4.y, a4.z, a4.w};
      float bv[4] = {b4.x, b4.y, b4.z, b4.w};
      #pragma unroll
      for (int i = 0; i < 4; ++i)
        #pragma unroll
        for (int j = 0; j < 4; ++j)
          acc[i][j] = fmaf(av[i], bv[j], acc[i][j]);
    }
  }
  #pragma unroll
  for (int i = 0; i < 4; ++i) {
    int o = o0 + ty * 4 + i;
    if constexpr (BF16OUT) {
      float sc = ((o % 96) < 32) ? 0.03125f : 1.0f;   // q rows only
      ushort* op = (ushort*)OutV + (size_t)b * O * HW + (size_t)o * HW + t0 + tx * 4;
      ushort4 r;
      r.x = f2bf(acc[i][0] * sc); r.y = f2bf(acc[i][1] * sc);
      r.z = f2bf(acc[i][2] * sc); r.w = f2bf(acc[i][3] * sc);
      *(ushort4*)op = r;
    } else {
      float* op = (float*)OutV + (size_t)b * O * HW + (size_t)o * HW + t0 + tx * 4;
      float4 r;
      r.x = acc[i][0]; r.y = acc[i][1]; r.z = acc[i][2]; r.w = acc[i][3];
      if (EPI) {
        float bs = bias[o];
        const float4 rv = *(const float4*)(resid + (size_t)b * CC * HW + (size_t)o * HW + t0 + tx * 4);
        r.x += bs + rv.x; r.y += bs + rv.y; r.z += bs + rv.z; r.w += bs + rv.w;
      }
      *(float4*)op = r;
    }
  }
}

// ---------------- MFMA flash attention ----------------
// qkv: bf16, per (b,h): Q=[32c][1024t] (prescaled 1/32), K=[32c][1024s], V=[32c][1024s].
// Block: 256 thr (4 waves), 64 queries. s-tiles of 64.
__global__ __launch_bounds__(256) void attn_mfma(const ushort* __restrict__ qkv,
                                                 float* __restrict__ hout) {
  int tb = blockIdx.x, h = blockIdx.y, b = blockIdx.z;
  const ushort* base = qkv + ((size_t)b * 384 + (size_t)h * 96) * HW;
  const ushort* Qg = base;
  const ushort* Kg = base + 32 * HW;
  const ushort* Vg = base + 64 * HW;
  int t0 = tb * 64;

  __shared__ ushort Qs[64 * 40];   // [t][c] stride 40
  __shared__ ushort Ks[64 * 40];   // [s][c] stride 40
  __shared__ ushort Vs[32 * 72];   // [c][s] stride 72
  __shared__ ushort Ps[64 * 72];   // [t][s] stride 72
  __shared__ float corrs[64], lsums[64];

  int tid = threadIdx.x;
  int lane = tid & 63, w = tid >> 6;
  int lg = lane >> 4, lc = lane & 15;

  { // stage Q transposed -> [t][c]
    int t = tid & 63, cq = tid >> 6;
    union { ushort u[8]; uint4 v; } tmp;
    #pragma unroll
    for (int i = 0; i < 8; ++i) tmp.u[i] = Qg[(size_t)(cq * 8 + i) * HW + t0 + t];
    *(uint4*)&Qs[t * 40 + cq * 8] = tmp.v;
  }
  __syncthreads();
  fragAB aq = *(fragAB*)&Qs[(w * 16 + lc) * 40 + lg * 8];

  fragC acc0 = {0.f, 0.f, 0.f, 0.f}, acc1 = {0.f, 0.f, 0.f, 0.f};
  float m[4] = {-1e30f, -1e30f, -1e30f, -1e30f};
  float ln[4] = {0.f, 0.f, 0.f, 0.f};
  int csub = w & 1;
  int tt0 = (w >> 1) * 2;

  for (int s0 = 0; s0 < HW; s0 += 64) {
    __syncthreads();
    { // stage K transposed -> [s][c]
      int s = tid & 63, cq = tid >> 6;
      union { ushort u[8]; uint4 v; } tmp;
      #pragma unroll
      for (int i = 0; i < 8; ++i) tmp.u[i] = Kg[(size_t)(cq * 8 + i) * HW + s0 + s];
      *(uint4*)&Ks[s * 40 + cq * 8] = tmp.v;
    }
    { // stage V natural [c][s]
      int c = tid >> 3, sq = tid & 7;
      uint4 vv = *(const uint4*)&Vg[(size_t)c * HW + s0 + sq * 8];
      *(uint4*)&Vs[c * 72 + sq * 8] = vv;
    }
    __syncthreads();

    // QK^T: wave w owns t-rows [w*16, w*16+16)
    fragC sfr[4];
    #pragma unroll
    for (int j = 0; j < 4; ++j) {
      fragAB bk = *(fragAB*)&Ks[(j * 16 + lc) * 40 + lg * 8];
      fragC z = {0.f, 0.f, 0.f, 0.f};
      sfr[j] = __builtin_amdgcn_mfma_f32_16x16x32_bf16(aq, bk, z, 0, 0, 0);
    }
    // online softmax (rows t = w*16 + lg*4 + r, cols s = j*16 + lc)
    #pragma unroll
    for (int r = 0; r < 4; ++r) {
      float mx = fmaxf(fmaxf(sfr[0][r], sfr[1][r]), fmaxf(sfr[2][r], sfr[3][r]));
      #pragma unroll
      for (int off = 1; off < 16; off <<= 1) mx = fmaxf(mx, __shfl_xor(mx, off, 64));
      float mn = fmaxf(m[r], mx);
      float corr = __expf(m[r] - mn);
      m[r] = mn;
      float p0 = __expf(sfr[0][r] - mn), p1 = __expf(sfr[1][r] - mn);
      float p2 = __expf(sfr[2][r] - mn), p3 = __expf(sfr[3][r] - mn);
      float rs = p0 + p1 + p2 + p3;
      #pragma unroll
      for (int off = 1; off < 16; off <<= 1) rs += __shfl_xor(rs, off, 64);
      ln[r] = ln[r] * corr + rs;
      int trow = w * 16 + lg * 4 + r;
      if (lc == 0) corrs[trow] = corr;
      Ps[trow * 72 +  0 + lc] = f2bf(p0);
      Ps[trow * 72 + 16 + lc] = f2bf(p1);
      Ps[trow * 72 + 32 + lc] = f2bf(p2);
      Ps[trow * 72 + 48 + lc] = f2bf(p3);
    }
    __syncthreads();

    // PV: wave w owns c-sub (w&1), t-subs {tt0, tt0+1}
    float c0 = corrs[tt0 * 16 + lc];
    float c1 = corrs[tt0 * 16 + 16 + lc];
    #pragma unroll
    for (int r = 0; r < 4; ++r) { acc0[r] *= c0; acc1[r] *= c1; }
    #pragma unroll
    for (int ks = 0; ks < 2; ++ks) {
      fragAB av  = *(fragAB*)&Vs[(csub * 16 + lc) * 72 + ks * 32 + lg * 8];
      fragAB bp0 = *(fragAB*)&Ps[(tt0 * 16 + lc) * 72 + ks * 32 + lg * 8];
      fragAB bp1 = *(fragAB*)&Ps[((tt0 + 1) * 16 + lc) * 72 + ks * 32 + lg * 8];
      acc0 = __builtin_amdgcn_mfma_f32_16x16x32_bf16(av, bp0, acc0, 0, 0, 0);
      acc1 = __builtin_amdgcn_mfma_f32_16x16x32_bf16(av, bp1, acc1, 0, 0, 0);
    }
  }

  if (lc == 0) {
    #pragma unroll
    for (int r = 0; r < 4; ++r) lsums[w * 16 + lg * 4 + r] = ln[r];
  }
  __syncthreads();
  float i0 = 1.f / lsums[tt0 * 16 + lc];
  float i1 = 1.f / lsums[tt0 * 16 + 16 + lc];
  #pragma unroll
  for (int r = 0; r < 4; ++r) {
    int c = h * 32 + csub * 16 + lg * 4 + r;
    hout[((size_t)b * CC + c) * HW + t0 + tt0 * 16 + lc]       = acc0[r] * i0;
    hout[((size_t)b * CC + c) * HW + t0 + (tt0 + 1) * 16 + lc] = acc1[r] * i1;
  }
}

extern "C" void kernel_launch(void* const* d_in, const int* in_sizes, int n_in,
                              void* d_out, int out_size, void* d_ws, size_t ws_size,
                              hipStream_t stream) {
  (void)in_sizes; (void)n_in; (void)out_size; (void)ws_size;
  const float* x     = (const float*)d_in[0];
  const float* gw    = (const float*)d_in[1];
  const float* gb    = (const float*)d_in[2];
  const float* qkvw  = (const float*)d_in[3];
  const float* projw = (const float*)d_in[4];
  const float* projb = (const float*)d_in[5];
  float* out = (float*)d_out;

  float* xn       = (float*)d_ws;                         // 16 MB fp32, reused as hout
  ushort* qkv16   = (ushort*)(xn + (size_t)BB * CC * HW); // 24 MB bf16

  gn_kernel<<<dim3(BB * NG), 256, 0, stream>>>(x, gw, gb, xn);
  gemm_kernel<0, 1><<<dim3(HW / 64, 384 / 64, BB), 256, 0, stream>>>(qkvw, xn, qkv16, 384, nullptr, nullptr);
  attn_mfma<<<dim3(HW / 64, 4, BB), 256, 0, stream>>>(qkv16, xn);
  gemm_kernel<1, 0><<<dim3(HW / 64, CC / 64, BB), 256, 0, stream>>>(projw, xn, out, CC, projb, x);
}

// Round 4
// 119.485 us; speedup vs baseline: 3.3922x; 1.4854x over previous
//
#include <hip/hip_runtime.h>
#include <math.h>

#define BB 32
#define CC 128
#define HW 1024
#define NG 32
#define TPG 4096
#define QSZ ((size_t)BB * 4 * HW * 32)   // elems per Q/K/V bf16 buffer

typedef __attribute__((ext_vector_type(8))) short fragAB;
typedef __attribute__((ext_vector_type(4))) float fragC;

__device__ __forceinline__ ushort f2bf(float f) {
  union { float f; uint u; } v; v.f = f;
  uint r = v.u + 0x7FFFu + ((v.u >> 16) & 1u);
  return (ushort)(r >> 16);
}
// pack two f32 -> two bf16 (truncation) in one v_perm_b32
__device__ __forceinline__ uint pack2(float lo, float hi) {
  return __builtin_amdgcn_perm(__float_as_uint(hi), __float_as_uint(lo), 0x07060302u);
}

// ---------------- GroupNorm ----------------
__global__ __launch_bounds__(256) void gn_kernel(const float* __restrict__ x,
    const float* __restrict__ gw, const float* __restrict__ gb,
    float* __restrict__ xn) {
  int blk = blockIdx.x;          // b*NG + g
  int b = blk >> 5, g = blk & 31;
  const float4* xp4 = (const float4*)(x + ((size_t)(b * CC + g * 4)) * HW);
  float s = 0.f, s2 = 0.f;
  float4 v[4];
  #pragma unroll
  for (int i = 0; i < 4; ++i) {
    v[i] = xp4[threadIdx.x + i * 256];
    s  += v[i].x + v[i].y + v[i].z + v[i].w;
    s2 += v[i].x * v[i].x + v[i].y * v[i].y + v[i].z * v[i].z + v[i].w * v[i].w;
  }
  #pragma unroll
  for (int off = 32; off; off >>= 1) {
    s  += __shfl_down(s, off, 64);
    s2 += __shfl_down(s2, off, 64);
  }
  __shared__ float ls[8], ls2[8];
  int lane = threadIdx.x & 63, wid = threadIdx.x >> 6;
  if (lane == 0) { ls[wid] = s; ls2[wid] = s2; }
  __syncthreads();
  if (threadIdx.x == 0) {
    float a  = ls[0] + ls[1] + ls[2] + ls[3];
    float a2 = ls2[0] + ls2[1] + ls2[2] + ls2[3];
    float mu = a * (1.f / TPG);
    float var = a2 * (1.f / TPG) - mu * mu;
    ls[0] = mu;
    ls2[0] = rsqrtf(var + 1e-5f);
  }
  __syncthreads();
  float mu = ls[0], rstd = ls2[0];
  float4* xo4 = (float4*)(xn + ((size_t)(b * CC + g * 4)) * HW);
  #pragma unroll
  for (int i = 0; i < 4; ++i) {
    int idx = threadIdx.x + i * 256;
    int c = g * 4 + (idx >> 8);
    float w = gw[c], bv = gb[c];
    float4 o;
    o.x = (v[i].x - mu) * rstd * w + bv;
    o.y = (v[i].y - mu) * rstd * w + bv;
    o.z = (v[i].z - mu) * rstd * w + bv;
    o.w = (v[i].w - mu) * rstd * w + bv;
    xo4[idx] = o;
  }
}

// ---------------- Tiled fp32 GEMM: Out[o,t] = sum_c A[o,c] * X[c,t] ----------------
// BF16OUT: scatter to frag-ready bf16 buffers: Q[bh][t][c] (q scaled 1/32),
//          K[bh][s][c], V[bh][c][s]. OutV = Q base; K = Q+QSZ; V = Q+2*QSZ.
// EPI: Out += bias[o] + resid[o,t] (fp32 out).
template<int EPI, int BF16OUT>
__global__ __launch_bounds__(256) void gemm_kernel(
    const float* __restrict__ A, const float* __restrict__ Xin,
    void* __restrict__ OutV, int O,
    const float* __restrict__ bias, const float* __restrict__ resid) {
  int b = blockIdx.z;
  int o0 = blockIdx.y * 64;
  int t0 = blockIdx.x * 64;
  const float* X = Xin + (size_t)b * CC * HW;

  __shared__ float Ws[32][68];
  __shared__ float Xs[32][68];
  int tx = threadIdx.x & 15, ty = threadIdx.x >> 4;
  float acc[4][4] = {};

  for (int kc = 0; kc < CC; kc += 32) {
    __syncthreads();
    #pragma unroll
    for (int j = 0; j < 2; ++j) {
      int f = threadIdx.x + j * 256;
      int wrow = f >> 3, wk = (f & 7) * 4;
      float4 wv = *(const float4*)&A[(size_t)(o0 + wrow) * CC + kc + wk];
      Ws[wk + 0][wrow] = wv.x; Ws[wk + 1][wrow] = wv.y;
      Ws[wk + 2][wrow] = wv.z; Ws[wk + 3][wrow] = wv.w;
      int xrow = f >> 4, xt = (f & 15) * 4;
      float4 xv = *(const float4*)&X[(size_t)(kc + xrow) * HW + t0 + xt];
      *(float4*)&Xs[xrow][xt] = xv;
    }
    __syncthreads();
    #pragma unroll
    for (int k = 0; k < 32; ++k) {
      float4 a4 = *(const float4*)&Ws[k][ty * 4];
      float4 b4 = *(const float4*)&Xs[k][tx * 4];
      float av[4] = {a4.x, a4.y, a4.z, a4.w};
      float bv[4] = {b4.x, b4.y, b4.z, b4.w};
      #pragma unroll
      for (int i = 0; i < 4; ++i)
        #pragma unroll
        for (int j = 0; j < 4; ++j)
          acc[i][j] = fmaf(av[i], bv[j], acc[i][j]);
    }
  }
  if constexpr (BF16OUT) {
    int reg = blockIdx.y * 2 + (ty >> 3);   // o/32
    int hh = reg / 3, kind = reg % 3;       // 0=q,1=k,2=v
    int c0 = (ty & 7) * 4;
    size_t bh = (size_t)b * 4 + hh;
    ushort* Qb = (ushort*)OutV;
    if (kind == 2) {
      ushort* Vb = Qb + 2 * QSZ;
      #pragma unroll
      for (int i = 0; i < 4; ++i) {
        ushort4 rv;
        rv.x = f2bf(acc[i][0]); rv.y = f2bf(acc[i][1]);
        rv.z = f2bf(acc[i][2]); rv.w = f2bf(acc[i][3]);
        *(ushort4*)&Vb[(bh * 32 + c0 + i) * HW + t0 + tx * 4] = rv;
      }
    } else {
      float sc = (kind == 0) ? 0.03125f : 1.0f;
      ushort* dst = (kind == 0) ? Qb : (Qb + QSZ);
      #pragma unroll
      for (int jt = 0; jt < 4; ++jt) {
        int t = t0 + tx * 4 + jt;
        ushort4 rv;
        rv.x = f2bf(acc[0][jt] * sc); rv.y = f2bf(acc[1][jt] * sc);
        rv.z = f2bf(acc[2][jt] * sc); rv.w = f2bf(acc[3][jt] * sc);
        *(ushort4*)&dst[(bh * HW + t) * 32 + c0] = rv;
      }
    }
  } else {
    #pragma unroll
    for (int i = 0; i < 4; ++i) {
      int o = o0 + ty * 4 + i;
      float* op = (float*)OutV + (size_t)b * O * HW + (size_t)o * HW + t0 + tx * 4;
      float4 r;
      r.x = acc[i][0]; r.y = acc[i][1]; r.z = acc[i][2]; r.w = acc[i][3];
      if (EPI) {
        float bs = bias[o];
        const float4 rv = *(const float4*)(resid + (size_t)b * CC * HW + (size_t)o * HW + t0 + tx * 4);
        r.x += bs + rv.x; r.y += bs + rv.y; r.z += bs + rv.z; r.w += bs + rv.w;
      }
      *(float4*)op = r;
    }
  }
}

// ---------------- MFMA flash attention v2 ----------------
// Frag-ready inputs. Block = 4 waves x 32 queries = 128 t. Swapped QK^T
// (S^T, col=t), reg softmax, wave-private Ps, 1 barrier/s-tile.
__global__ __launch_bounds__(256, 4) void attn2(
    const ushort* __restrict__ Qb, const ushort* __restrict__ Kb,
    const ushort* __restrict__ Vb, float* __restrict__ hout) {
  __shared__ ushort Kl[2][64 * 32];     // [s][c] linear
  __shared__ ushort Vl[2][32 * 72];     // [c][s] pad 72
  __shared__ ushort Ps[4][16 * 72];     // per-wave [t][s] pad 72

  int lin = blockIdx.x;
  int wl = (lin & 7) * 128 + (lin >> 3);   // XCD swizzle: head stays on one XCD
  int tb = wl & 7;
  int bh = wl >> 3;
  int h = bh & 3, b = bh >> 2;

  int tid = threadIdx.x;
  int w = tid >> 6, lane = tid & 63, lc = lane & 15, lg = lane >> 4;

  const ushort* Qg = Qb + (size_t)bh * HW * 32;
  const ushort* Kg = Kb + (size_t)bh * HW * 32;
  const ushort* Vg = Vb + (size_t)bh * HW * 32;
  int t0 = tb * 128 + w * 32;

  fragAB q0 = *(const fragAB*)&Qg[(size_t)(t0 + lc) * 32 + lg * 8];
  fragAB q1 = *(const fragAB*)&Qg[(size_t)(t0 + 16 + lc) * 32 + lg * 8];

  fragC a00 = {0.f,0.f,0.f,0.f}, a01 = {0.f,0.f,0.f,0.f};
  fragC a10 = {0.f,0.f,0.f,0.f}, a11 = {0.f,0.f,0.f,0.f};
  float m0 = -1e30f, m1 = -1e30f, l0 = 0.f, l1 = 0.f;

  int vrow = tid >> 3, vcol = (tid & 7) * 8;
  // stage tile 0
  uint4 kreg = *(const uint4*)&Kg[tid * 8];
  uint4 vreg = *(const uint4*)&Vg[(size_t)vrow * HW + vcol];
  *(uint4*)&Kl[0][tid * 8] = kreg;
  *(uint4*)&Vl[0][vrow * 72 + vcol] = vreg;
  __syncthreads();

  for (int i = 0; i < 16; ++i) {
    int cur = i & 1, nxt = cur ^ 1;
    if (i < 15) {
      int sn = (i + 1) * 64;
      kreg = *(const uint4*)&Kg[sn * 32 + tid * 8];
      vreg = *(const uint4*)&Vg[(size_t)vrow * HW + sn + vcol];
    }
    fragAB kf[4];
    #pragma unroll
    for (int j = 0; j < 4; ++j)
      kf[j] = *(fragAB*)&Kl[cur][(j * 16 + lc) * 32 + lg * 8];
    fragAB vf[2][2];
    #pragma unroll
    for (int cs = 0; cs < 2; ++cs)
      #pragma unroll
      for (int ks = 0; ks < 2; ++ks)
        vf[cs][ks] = *(fragAB*)&Vl[cur][(cs * 16 + lc) * 72 + ks * 32 + lg * 8];

    #pragma unroll
    for (int ts = 0; ts < 2; ++ts) {
      fragAB qf = ts ? q1 : q0;
      float m = ts ? m1 : m0, l = ts ? l1 : l0;
      fragC S[4];
      #pragma unroll
      for (int j = 0; j < 4; ++j) {
        fragC z = {0.f,0.f,0.f,0.f};
        S[j] = __builtin_amdgcn_mfma_f32_16x16x32_bf16(kf[j], qf, z, 0, 0, 0);
      }
      float tmax = -1e30f;
      #pragma unroll
      for (int j = 0; j < 4; ++j)
        #pragma unroll
        for (int r = 0; r < 4; ++r) tmax = fmaxf(tmax, S[j][r]);
      tmax = fmaxf(tmax, __shfl_xor(tmax, 16));
      tmax = fmaxf(tmax, __shfl_xor(tmax, 32));
      float mn = fmaxf(m, tmax);
      float corr = __expf(m - mn);
      m = mn;
      float rs = 0.f;
      #pragma unroll
      for (int j = 0; j < 4; ++j) {
        float p0 = __expf(S[j][0] - mn), p1 = __expf(S[j][1] - mn);
        float p2 = __expf(S[j][2] - mn), p3 = __expf(S[j][3] - mn);
        rs += (p0 + p1) + (p2 + p3);
        uint2 wv;
        wv.x = pack2(p0, p1);
        wv.y = pack2(p2, p3);
        *(uint2*)&Ps[w][lc * 72 + j * 16 + lg * 4] = wv;   // b64, wave-private
      }
      rs += __shfl_xor(rs, 16);
      rs += __shfl_xor(rs, 32);
      l = l * corr + rs;
      fragC* aA = ts ? &a01 : &a00;
      fragC* aB = ts ? &a11 : &a10;
      #pragma unroll
      for (int r = 0; r < 4; ++r) { (*aA)[r] *= corr; (*aB)[r] *= corr; }
      fragAB bp0 = *(fragAB*)&Ps[w][lc * 72 + 0 * 32 + lg * 8];
      fragAB bp1 = *(fragAB*)&Ps[w][lc * 72 + 1 * 32 + lg * 8];
      *aA = __builtin_amdgcn_mfma_f32_16x16x32_bf16(vf[0][0], bp0, *aA, 0, 0, 0);
      *aA = __builtin_amdgcn_mfma_f32_16x16x32_bf16(vf[0][1], bp1, *aA, 0, 0, 0);
      *aB = __builtin_amdgcn_mfma_f32_16x16x32_bf16(vf[1][0], bp0, *aB, 0, 0, 0);
      *aB = __builtin_amdgcn_mfma_f32_16x16x32_bf16(vf[1][1], bp1, *aB, 0, 0, 0);
      if (ts) { m1 = m; l1 = l; } else { m0 = m; l0 = l; }
    }

    if (i < 15) {
      *(uint4*)&Kl[nxt][tid * 8] = kreg;
      *(uint4*)&Vl[nxt][vrow * 72 + vcol] = vreg;
    }
    __syncthreads();
  }

  float il0 = 1.f / l0, il1 = 1.f / l1;
  #pragma unroll
  for (int r = 0; r < 4; ++r) {
    int cA = h * 32 + lg * 4 + r;
    int cB = cA + 16;
    hout[((size_t)b * CC + cA) * HW + t0 + lc]      = a00[r] * il0;
    hout[((size_t)b * CC + cB) * HW + t0 + lc]      = a10[r] * il0;
    hout[((size_t)b * CC + cA) * HW + t0 + 16 + lc] = a01[r] * il1;
    hout[((size_t)b * CC + cB) * HW + t0 + 16 + lc] = a11[r] * il1;
  }
}

extern "C" void kernel_launch(void* const* d_in, const int* in_sizes, int n_in,
                              void* d_out, int out_size, void* d_ws, size_t ws_size,
                              hipStream_t stream) {
  (void)in_sizes; (void)n_in; (void)out_size; (void)ws_size;
  const float* x     = (const float*)d_in[0];
  const float* gw    = (const float*)d_in[1];
  const float* gb    = (const float*)d_in[2];
  const float* qkvw  = (const float*)d_in[3];
  const float* projw = (const float*)d_in[4];
  const float* projb = (const float*)d_in[5];
  float* out = (float*)d_out;

  float* xn   = (float*)d_ws;                           // 16 MB fp32, reused as hout
  ushort* Qb  = (ushort*)(xn + (size_t)BB * CC * HW);   // 3 x 8 MB bf16
  ushort* Kb  = Qb + QSZ;
  ushort* Vb  = Qb + 2 * QSZ;

  gn_kernel<<<dim3(BB * NG), 256, 0, stream>>>(x, gw, gb, xn);
  gemm_kernel<0, 1><<<dim3(HW / 64, 384 / 64, BB), 256, 0, stream>>>(qkvw, xn, Qb, 384, nullptr, nullptr);
  attn2<<<dim3(1024), 256, 0, stream>>>(Qb, Kb, Vb, xn);
  gemm_kernel<1, 0><<<dim3(HW / 64, CC / 64, BB), 256, 0, stream>>>(projw, xn, out, CC, projb, x);
}

// Round 5
// 85.451 us; speedup vs baseline: 4.7433x; 1.3983x over previous
//
#include <hip/hip_runtime.h>
#include <math.h>

#define BB 32
#define CC 128
#define HW 1024
#define NG 32
#define TPG 4096
#define QSZ ((size_t)BB * 4 * HW * 32)   // elems per Q/K/V bf16 buffer

typedef __attribute__((ext_vector_type(8))) short fragAB;
typedef __attribute__((ext_vector_type(4))) float fragC;

__device__ __forceinline__ ushort f2bf(float f) {
  union { float f; uint u; } v; v.f = f;
  uint r = v.u + 0x7FFFu + ((v.u >> 16) & 1u);
  return (ushort)(r >> 16);
}
// pack two f32 -> two bf16 (truncation) in one v_perm_b32
__device__ __forceinline__ uint pack2(float lo, float hi) {
  return __builtin_amdgcn_perm(__float_as_uint(hi), __float_as_uint(lo), 0x07060302u);
}

// ---------------- weight fp32 -> bf16 prep ----------------
__global__ __launch_bounds__(256) void prep_w(const float* __restrict__ qkvw,
    const float* __restrict__ projw, ushort* __restrict__ wq16,
    ushort* __restrict__ wp16) {
  int idx = blockIdx.x * 256 + threadIdx.x;       // grid 256 -> 65536
  if (idx < 49152) wq16[idx] = f2bf(qkvw[idx]);
  else             wp16[idx - 49152] = f2bf(projw[idx - 49152]);
}

// ---------------- GroupNorm stats: mu, rstd per (b,g) ----------------
__global__ __launch_bounds__(256) void gn_stats(const float* __restrict__ x,
                                                float2* __restrict__ stats) {
  int blk = blockIdx.x;          // b*NG + g
  int b = blk >> 5, g = blk & 31;
  const float4* xp4 = (const float4*)(x + ((size_t)(b * CC + g * 4)) * HW);
  float s = 0.f, s2 = 0.f;
  #pragma unroll
  for (int i = 0; i < 4; ++i) {
    float4 v = xp4[threadIdx.x + i * 256];
    s  += v.x + v.y + v.z + v.w;
    s2 += v.x * v.x + v.y * v.y + v.z * v.z + v.w * v.w;
  }
  #pragma unroll
  for (int off = 32; off; off >>= 1) {
    s  += __shfl_down(s, off, 64);
    s2 += __shfl_down(s2, off, 64);
  }
  __shared__ float ls[4], ls2[4];
  int lane = threadIdx.x & 63, wid = threadIdx.x >> 6;
  if (lane == 0) { ls[wid] = s; ls2[wid] = s2; }
  __syncthreads();
  if (threadIdx.x == 0) {
    float a  = ls[0] + ls[1] + ls[2] + ls[3];
    float a2 = ls2[0] + ls2[1] + ls2[2] + ls2[3];
    float mu = a * (1.f / TPG);
    float var = a2 * (1.f / TPG) - mu * mu;
    stats[blk] = make_float2(mu, rsqrtf(var + 1e-5f));
  }
}

// ---------------- GN apply + transpose: x[b][c][t] -> xt16[b][t][c] bf16 ----------------
__global__ __launch_bounds__(256) void gn_apply(const float* __restrict__ x,
    const float2* __restrict__ stats, const float* __restrict__ gw,
    const float* __restrict__ gb, ushort* __restrict__ xt16) {
  __shared__ ushort Xs[64][136];   // pad 136: aligned uint4 readback, low-conflict writes
  int b = blockIdx.x >> 4, t0 = (blockIdx.x & 15) * 64;
  int tid = threadIdx.x;
  int tq = tid & 15, cg = (tid >> 4) & 3, wv = tid >> 6;

  #pragma unroll
  for (int iter = 0; iter < 8; ++iter) {
    int c = wv * 4 + cg + iter * 16;
    float2 st = stats[b * 32 + (c >> 2)];
    float wsc = gw[c] * st.y;
    float bsc = gb[c] - st.x * wsc;
    const float* xp = x + ((size_t)b * CC + c) * HW + t0;
    #pragma unroll
    for (int j = 0; j < 4; ++j) {
      int t = tq + 16 * j;               // lanes consecutive in t
      Xs[t][c] = f2bf(xp[t] * wsc + bsc);
    }
  }
  __syncthreads();
  #pragma unroll
  for (int it = 0; it < 4; ++it) {
    int row = (tid >> 4) + it * 16;
    int c8 = tid & 15;
    uint4 v = *(uint4*)&Xs[row][c8 * 8];
    *(uint4*)&xt16[((size_t)b * HW + t0 + row) * CC + c8 * 8] = v;
  }
}

// ---------------- MFMA GEMM: D[o,t] = sum_c W[o,c] * X[t,c] ----------------
// X16: [b][t][c] bf16 (t-major). PROJ=0: scatter to Q/K/V frag layouts (q *1/32).
// PROJ=1: out fp32 [b][o][t] = D + bias[o] + resid[b][o][t].
template<int PROJ>
__global__ __launch_bounds__(256) void mgemm(
    const ushort* __restrict__ W16, const ushort* __restrict__ X16,
    ushort* __restrict__ Qb, float* __restrict__ out,
    const float* __restrict__ bias, const float* __restrict__ resid) {
  __shared__ ushort Xs[64 * 128];    // 16KB, XOR-swizzled byte ^= ((row&7)<<4)
  int b = blockIdx.z, o0 = blockIdx.y * 64, t0 = blockIdx.x * 64;
  int tid = threadIdx.x;
  int lane = tid & 63, w = tid >> 6, lc = lane & 15, lg = lane >> 4;
  int wo = w >> 1, wt = w & 1;

  // A-frags direct from global (weights L1/L2-resident)
  fragAB af[2][4];
  #pragma unroll
  for (int i = 0; i < 2; ++i)
    #pragma unroll
    for (int kc = 0; kc < 4; ++kc)
      af[i][kc] = *(const fragAB*)&W16[(size_t)(o0 + wo * 32 + i * 16 + lc) * 128 + kc * 32 + lg * 8];

  { // stage X tile (contiguous 16KB) with XOR swizzle
    const char* src = (const char*)(X16 + ((size_t)b * HW + t0) * CC);
    char* dst = (char*)Xs;
    #pragma unroll
    for (int it = 0; it < 4; ++it) {
      int flat = tid * 16 + it * 4096;
      uint4 v = *(const uint4*)(src + flat);
      *(uint4*)(dst + (flat ^ (((flat >> 8) & 7) << 4))) = v;
    }
  }
  __syncthreads();

  fragC acc[2][2];
  #pragma unroll
  for (int i = 0; i < 2; ++i)
    #pragma unroll
    for (int j = 0; j < 2; ++j)
      acc[i][j] = (fragC){0.f, 0.f, 0.f, 0.f};

  #pragma unroll
  for (int kc = 0; kc < 4; ++kc) {
    fragAB bf[2];
    #pragma unroll
    for (int j = 0; j < 2; ++j) {
      int row = wt * 32 + j * 16 + lc;
      int byt = (row * 256 + kc * 64 + lg * 16) ^ ((row & 7) << 4);
      bf[j] = *(const fragAB*)((const char*)Xs + byt);
    }
    #pragma unroll
    for (int i = 0; i < 2; ++i)
      #pragma unroll
      for (int j = 0; j < 2; ++j)
        acc[i][j] = __builtin_amdgcn_mfma_f32_16x16x32_bf16(af[i][kc], bf[j], acc[i][j], 0, 0, 0);
  }

  if constexpr (PROJ == 0) {
    #pragma unroll
    for (int i = 0; i < 2; ++i) {
      int ob = o0 + wo * 32 + i * 16;
      int blk = ob >> 5;                 // 0..11
      int hh = blk / 3, kind = blk % 3;  // 0=q,1=k,2=v
      int cb = ob & 16;
      size_t bh = (size_t)b * 4 + hh;
      float sc = (kind == 0) ? 0.03125f : 1.f;
      #pragma unroll
      for (int j = 0; j < 2; ++j) {
        int t = t0 + wt * 32 + j * 16 + lc;
        if (kind < 2) {
          ushort* dst = (kind == 0) ? Qb : (Qb + QSZ);
          ushort4 rv;
          rv.x = f2bf(acc[i][j][0] * sc); rv.y = f2bf(acc[i][j][1] * sc);
          rv.z = f2bf(acc[i][j][2] * sc); rv.w = f2bf(acc[i][j][3] * sc);
          *(ushort4*)&dst[(bh * HW + t) * 32 + cb + lg * 4] = rv;
        } else {
          ushort* Vb = Qb + 2 * QSZ;
          #pragma unroll
          for (int r = 0; r < 4; ++r)
            Vb[(bh * 32 + cb + lg * 4 + r) * HW + t] = f2bf(acc[i][j][r]);
        }
      }
    }
  } else {
    #pragma unroll
    for (int i = 0; i < 2; ++i)
      #pragma unroll
      for (int j = 0; j < 2; ++j) {
        int t = t0 + wt * 32 + j * 16 + lc;
        #pragma unroll
        for (int r = 0; r < 4; ++r) {
          int o = o0 + wo * 32 + i * 16 + lg * 4 + r;
          size_t idx = ((size_t)b * CC + o) * HW + t;
          out[idx] = acc[i][j][r] + bias[o] + resid[idx];
        }
      }
  }
}

// ---------------- MFMA flash attention ----------------
// Q[bh][t][c] (prescaled 1/32), K[bh][s][c], V[bh][c][s] bf16.
// Output: ao16[b][t][c] bf16 (t-major, frag-ready for proj GEMM).
__global__ __launch_bounds__(256, 4) void attn2(
    const ushort* __restrict__ Qb, const ushort* __restrict__ Kb,
    const ushort* __restrict__ Vb, ushort* __restrict__ ao16) {
  __shared__ ushort Kl[2][64 * 32];     // [s][c] linear
  __shared__ ushort Vl[2][32 * 72];     // [c][s] pad 72
  __shared__ ushort Ps[4][16 * 72];     // per-wave [t][s] pad 72
  __shared__ ushort Ol[128][40];        // [t][c] output transpose, pad 40

  int lin = blockIdx.x;
  int wl = (lin & 7) * 128 + (lin >> 3);   // XCD swizzle
  int tb = wl & 7;
  int bh = wl >> 3;
  int h = bh & 3, b = bh >> 2;

  int tid = threadIdx.x;
  int w = tid >> 6, lane = tid & 63, lc = lane & 15, lg = lane >> 4;

  const ushort* Qg = Qb + (size_t)bh * HW * 32;
  const ushort* Kg = Kb + (size_t)bh * HW * 32;
  const ushort* Vg = Vb + (size_t)bh * HW * 32;
  int t0 = tb * 128 + w * 32;

  fragAB q0 = *(const fragAB*)&Qg[(size_t)(t0 + lc) * 32 + lg * 8];
  fragAB q1 = *(const fragAB*)&Qg[(size_t)(t0 + 16 + lc) * 32 + lg * 8];

  fragC a00 = {0.f,0.f,0.f,0.f}, a01 = {0.f,0.f,0.f,0.f};
  fragC a10 = {0.f,0.f,0.f,0.f}, a11 = {0.f,0.f,0.f,0.f};
  float m0 = -1e30f, m1 = -1e30f, l0 = 0.f, l1 = 0.f;

  int vrow = tid >> 3, vcol = (tid & 7) * 8;
  uint4 kreg = *(const uint4*)&Kg[tid * 8];
  uint4 vreg = *(const uint4*)&Vg[(size_t)vrow * HW + vcol];
  *(uint4*)&Kl[0][tid * 8] = kreg;
  *(uint4*)&Vl[0][vrow * 72 + vcol] = vreg;
  __syncthreads();

  for (int i = 0; i < 16; ++i) {
    int cur = i & 1, nxt = cur ^ 1;
    if (i < 15) {
      int sn = (i + 1) * 64;
      kreg = *(const uint4*)&Kg[sn * 32 + tid * 8];
      vreg = *(const uint4*)&Vg[(size_t)vrow * HW + sn + vcol];
    }
    fragAB kf[4];
    #pragma unroll
    for (int j = 0; j < 4; ++j)
      kf[j] = *(fragAB*)&Kl[cur][(j * 16 + lc) * 32 + lg * 8];
    fragAB vf[2][2];
    #pragma unroll
    for (int cs = 0; cs < 2; ++cs)
      #pragma unroll
      for (int ks = 0; ks < 2; ++ks)
        vf[cs][ks] = *(fragAB*)&Vl[cur][(cs * 16 + lc) * 72 + ks * 32 + lg * 8];

    #pragma unroll
    for (int ts = 0; ts < 2; ++ts) {
      fragAB qf = ts ? q1 : q0;
      float m = ts ? m1 : m0, l = ts ? l1 : l0;
      fragC S[4];
      #pragma unroll
      for (int j = 0; j < 4; ++j) {
        fragC z = {0.f,0.f,0.f,0.f};
        S[j] = __builtin_amdgcn_mfma_f32_16x16x32_bf16(kf[j], qf, z, 0, 0, 0);
      }
      float tmax = -1e30f;
      #pragma unroll
      for (int j = 0; j < 4; ++j)
        #pragma unroll
        for (int r = 0; r < 4; ++r) tmax = fmaxf(tmax, S[j][r]);
      tmax = fmaxf(tmax, __shfl_xor(tmax, 16));
      tmax = fmaxf(tmax, __shfl_xor(tmax, 32));
      float mn = fmaxf(m, tmax);
      float corr = __expf(m - mn);
      m = mn;
      float rs = 0.f;
      #pragma unroll
      for (int j = 0; j < 4; ++j) {
        float p0 = __expf(S[j][0] - mn), p1 = __expf(S[j][1] - mn);
        float p2 = __expf(S[j][2] - mn), p3 = __expf(S[j][3] - mn);
        rs += (p0 + p1) + (p2 + p3);
        uint2 wv;
        wv.x = pack2(p0, p1);
        wv.y = pack2(p2, p3);
        *(uint2*)&Ps[w][lc * 72 + j * 16 + lg * 4] = wv;
      }
      rs += __shfl_xor(rs, 16);
      rs += __shfl_xor(rs, 32);
      l = l * corr + rs;
      fragC* aA = ts ? &a01 : &a00;
      fragC* aB = ts ? &a11 : &a10;
      #pragma unroll
      for (int r = 0; r < 4; ++r) { (*aA)[r] *= corr; (*aB)[r] *= corr; }
      fragAB bp0 = *(fragAB*)&Ps[w][lc * 72 + 0 * 32 + lg * 8];
      fragAB bp1 = *(fragAB*)&Ps[w][lc * 72 + 1 * 32 + lg * 8];
      *aA = __builtin_amdgcn_mfma_f32_16x16x32_bf16(vf[0][0], bp0, *aA, 0, 0, 0);
      *aA = __builtin_amdgcn_mfma_f32_16x16x32_bf16(vf[0][1], bp1, *aA, 0, 0, 0);
      *aB = __builtin_amdgcn_mfma_f32_16x16x32_bf16(vf[1][0], bp0, *aB, 0, 0, 0);
      *aB = __builtin_amdgcn_mfma_f32_16x16x32_bf16(vf[1][1], bp1, *aB, 0, 0, 0);
      if (ts) { m1 = m; l1 = l; } else { m0 = m; l0 = l; }
    }

    if (i < 15) {
      *(uint4*)&Kl[nxt][tid * 8] = kreg;
      *(uint4*)&Vl[nxt][vrow * 72 + vcol] = vreg;
    }
    __syncthreads();
  }

  // output: frags -> Ol[t][c] (bf16) -> coalesced global [b][t][c]
  float il0 = 1.f / l0, il1 = 1.f / l1;
  int tl = w * 32 + lc;
  #pragma unroll
  for (int r = 0; r < 4; ++r) {
    Ol[tl][lg * 4 + r]           = f2bf(a00[r] * il0);
    Ol[tl][16 + lg * 4 + r]      = f2bf(a10[r] * il0);
    Ol[tl + 16][lg * 4 + r]      = f2bf(a01[r] * il1);
    Ol[tl + 16][16 + lg * 4 + r] = f2bf(a11[r] * il1);
  }
  __syncthreads();
  int t0g = tb * 128;
  #pragma unroll
  for (int it = 0; it < 2; ++it) {
    int row = (tid >> 2) + it * 64;
    int q = tid & 3;
    uint4 v = *(uint4*)&Ol[row][q * 8];
    *(uint4*)&ao16[((size_t)b * HW + t0g + row) * CC + h * 32 + q * 8] = v;
  }
}

extern "C" void kernel_launch(void* const* d_in, const int* in_sizes, int n_in,
                              void* d_out, int out_size, void* d_ws, size_t ws_size,
                              hipStream_t stream) {
  (void)in_sizes; (void)n_in; (void)out_size; (void)ws_size;
  const float* x     = (const float*)d_in[0];
  const float* gw    = (const float*)d_in[1];
  const float* gb    = (const float*)d_in[2];
  const float* qkvw  = (const float*)d_in[3];
  const float* projw = (const float*)d_in[4];
  const float* projb = (const float*)d_in[5];
  float* out = (float*)d_out;

  char* wsb = (char*)d_ws;
  ushort* xt16 = (ushort*)wsb;                              // 8 MB (GN out, then attn out)
  ushort* Qb   = (ushort*)(wsb + ((size_t)8 << 20));        // 8 MB
  ushort* Kb   = Qb + QSZ;                                  // 8 MB
  ushort* Vb   = Qb + 2 * QSZ;                              // 8 MB
  ushort* wq16 = (ushort*)(wsb + ((size_t)32 << 20));       // 96 KB
  ushort* wp16 = (ushort*)(wsb + ((size_t)32 << 20) + (128 << 10)); // 32 KB
  float2* stats = (float2*)(wsb + ((size_t)32 << 20) + (256 << 10)); // 8 KB

  prep_w<<<dim3(256), 256, 0, stream>>>(qkvw, projw, wq16, wp16);
  gn_stats<<<dim3(BB * NG), 256, 0, stream>>>(x, stats);
  gn_apply<<<dim3(BB * 16), 256, 0, stream>>>(x, stats, gw, gb, xt16);
  mgemm<0><<<dim3(16, 6, BB), 256, 0, stream>>>(wq16, xt16, Qb, nullptr, nullptr, nullptr);
  attn2<<<dim3(1024), 256, 0, stream>>>(Qb, Kb, Vb, xt16);
  mgemm<1><<<dim3(16, 2, BB), 256, 0, stream>>>(wp16, xt16, nullptr, out, projb, x);
}